// Round 9
// baseline (355.472 us; speedup 1.0000x reference)
//
#include <hip/hip_runtime.h>

typedef _Float16 f16;
typedef _Float16 f16x4 __attribute__((ext_vector_type(4)));
typedef _Float16 f16x8 __attribute__((ext_vector_type(8)));
typedef __fp16 h2 __attribute__((ext_vector_type(2)));
typedef float f32x4 __attribute__((ext_vector_type(4)));
typedef float f32x16 __attribute__((ext_vector_type(16)));

#define MFMA16(a, b, c) __builtin_amdgcn_mfma_f32_16x16x32_f16(a, b, c, 0, 0, 0)
#define MFMA32(a, b, c) __builtin_amdgcn_mfma_f32_32x32x16_f16(a, b, c, 0, 0, 0)

#if defined(__has_builtin)
#if __has_builtin(__builtin_amdgcn_fdot2)
#define HAS_FDOT2 1
#endif
#endif

__device__ __forceinline__ int swzr(int row) { return ((row & 7) << 4) ^ ((row & 8) << 2); }

// ---------------- kernel 0: convert weights to fp16 ----------------
__global__ __launch_bounds__(256) void wcvt_k(
    const float* __restrict__ tw, const float* __restrict__ pw,
    const float* __restrict__ gw, const float* __restrict__ ww,
    f16* __restrict__ Wall, f16* __restrict__ Wepi) {
  int i = blockIdx.x * 256 + threadIdx.x;
  if (i < 384 * 256) {
    int c = i >> 8, cp = i & 255;
    float v = (c < 128) ? tw[c * 256 + cp]
            : (c < 256) ? pw[(c - 128) * 256 + cp]
                        : gw[(c - 256) * 256 + cp];
    Wall[i] = (f16)v;
  }
  int j = i - 384 * 256;
  if (j >= 0 && j < 256 * 128) Wepi[j] = (f16)ww[j];
}

// ---------------- kernel 1: projection GEMM, reads x natively ----------------
__global__ __launch_bounds__(256) void proj_k(
    const float* __restrict__ x, const f16* __restrict__ Wall,
    const float* __restrict__ tb, const float* __restrict__ pb,
    const float* __restrict__ gb, f16* __restrict__ Q, f16* __restrict__ K,
    f16* __restrict__ Vt) {
  __shared__ f16 xs[64 * 264];
  __shared__ f16 vs[128 * 65];
  int b = blockIdx.x >> 6, nt = blockIdx.x & 63;
  int nbase = nt * 64;
  int tid = threadIdx.x;

  int nq = tid & 15, kq0 = tid >> 4;
#pragma unroll
  for (int p = 0; p < 4; ++p) {
    int kq = kq0 + 16 * p;
    float4 ld[4];
#pragma unroll
    for (int j = 0; j < 4; ++j)
      ld[j] = *(const float4*)(x + ((size_t)b * 256 + 4 * kq + j) * 4096 + nbase + 4 * nq);
#pragma unroll
    for (int e = 0; e < 4; ++e) {
      f16x4 wv = {(f16)((&ld[0].x)[e]), (f16)((&ld[1].x)[e]), (f16)((&ld[2].x)[e]),
                  (f16)((&ld[3].x)[e])};
      *(f16x4*)(&xs[(4 * nq + e) * 264 + 4 * kq]) = wv;
    }
  }
  __syncthreads();

  int w = tid >> 6, lane = tid & 63;
  int lr = lane & 15, lhi = lane >> 4;
  f16x8 a[8];
#pragma unroll
  for (int ks = 0; ks < 8; ++ks)
    a[ks] = *(const f16x8*)(&xs[(w * 16 + lr) * 264 + ks * 32 + lhi * 8]);
  f32x4 acc[24];
#pragma unroll
  for (int ct = 0; ct < 24; ++ct) {
    acc[ct] = {0.f, 0.f, 0.f, 0.f};
    const f16x8* wr = (const f16x8*)(Wall + (size_t)(ct * 16 + lr) * 256);
#pragma unroll
    for (int ks = 0; ks < 8; ++ks) acc[ct] = MFMA16(a[ks], wr[ks * 4 + lhi], acc[ct]);
  }
  int nloc = w * 16 + lhi * 4;
#pragma unroll
  for (int ct = 0; ct < 24; ++ct) {
    int c = ct * 16 + lr;
    float bias = (c < 128) ? tb[c] : (c < 256) ? pb[c - 128] : gb[c - 256];
#pragma unroll
    for (int r = 0; r < 4; ++r) {
      float v = acc[ct][r] + bias;
      int n = nbase + nloc + r;
      if (c < 128)
        Q[((size_t)b * 4096 + n) * 128 + c] = (f16)v;
      else if (c < 256)
        K[((size_t)b * 4096 + n) * 128 + (c - 128)] = (f16)v;
      else
        vs[(c - 256) * 65 + nloc + r] = (f16)v;
    }
  }
  __syncthreads();
  f16* vo = Vt + (size_t)b * 128 * 4096 + nbase;
  for (int rep = 0; rep < 32; ++rep) {
    int idx = rep * 256 + threadIdx.x;
    int c = idx >> 6, j = idx & 63;
    vo[(size_t)c * 4096 + j] = vs[c * 65 + j];
  }
}

// ---------------- kernel 2: flash attention, KV-split-4, SINGLE-buffer 32KB LDS ----
// Occupancy plan: 32KB LDS -> >=3 blocks/CU; register diet + bounds(256,3) ->
// <=170 unified regs -> 3 waves/SIMD. 2 barriers/iter; T14 loads stay in regs
// across PV so the post-PV write lands just before the next tile needs it.
__global__ __launch_bounds__(256, 3) void attn_k(const f16* __restrict__ Q,
                                                 const f16* __restrict__ K,
                                                 const f16* __restrict__ Vt,
                                                 f16* __restrict__ Yp,
                                                 float2* __restrict__ ml) {
  __shared__ f16 Ks[64 * 128];
  __shared__ f16 Vs[128 * 64];
  const float L = 1.44269504f;
  int swzid = ((blockIdx.x & 7) << 7) | ((int)blockIdx.x >> 3);
  int b = swzid >> 7, rem = swzid & 127;
  int qt = rem >> 2, s = rem & 3;
  int qbase = qt * 128;
  int kvbase = s << 10;
  int tid = threadIdx.x;
  int w = tid >> 6, lane = tid & 63;
  int col = lane & 31, hi = lane >> 5;

  const f16* Qr = Q + ((size_t)b * 4096 + qbase + w * 32 + col) * 128;
  f16x8 bq[8];
#pragma unroll
  for (int ks = 0; ks < 8; ++ks) bq[ks] = *(const f16x8*)(Qr + ks * 16 + hi * 8);

  f32x16 yacc[4];
#pragma unroll
  for (int dt = 0; dt < 4; ++dt)
#pragma unroll
    for (int r = 0; r < 16; ++r) yacc[dt][r] = 0.f;
  float lv[4] = {0.f, 0.f, 0.f, 0.f};
  float m = -1e30f, nmL = 1e30f;

  const f16* Kbase = K + (size_t)b * 4096 * 128;
  const f16* Vbase = Vt + (size_t)b * 128 * 4096;

  int krow = tid >> 4, kcolb = (tid & 15) * 16;
  int vrow = tid >> 1, h2i = tid & 1;
  int sv = swzr(vrow);

  // prologue: stage tile 0
  {
    const f16* Kt = Kbase + (size_t)kvbase * 128;
    f16x8 kr[4], vr[4];
#pragma unroll
    for (int r = 0; r < 4; ++r) kr[r] = *(const f16x8*)(Kt + (r * 256 + tid) * 8);
#pragma unroll
    for (int u = 0; u < 4; ++u)
      vr[u] = *(const f16x8*)(Vbase + (size_t)vrow * 4096 + kvbase + h2i * 32 + u * 8);
#pragma unroll
    for (int r = 0; r < 4; ++r) {
      int row = r * 16 + krow;
      *(f16x8*)((char*)Ks + row * 256 + (kcolb ^ swzr(row))) = kr[r];
    }
    f16x8 c0, c1, c2, c3;
#pragma unroll
    for (int e = 0; e < 4; ++e) {
      c0[e] = vr[0][e];     c0[4 + e] = vr[1][e];
      c1[e] = vr[0][4 + e]; c1[4 + e] = vr[1][4 + e];
      c2[e] = vr[2][e];     c2[4 + e] = vr[3][e];
      c3[e] = vr[2][4 + e]; c3[4 + e] = vr[3][4 + e];
    }
    char* vb = (char*)Vs + vrow * 128;
    *(f16x8*)(vb + ((h2i * 64 + 0) ^ sv)) = c0;
    *(f16x8*)(vb + ((h2i * 64 + 16) ^ sv)) = c1;
    *(f16x8*)(vb + ((h2i * 64 + 32) ^ sv)) = c2;
    *(f16x8*)(vb + ((h2i * 64 + 48) ^ sv)) = c3;
  }
  __syncthreads();

  for (int t = 0; t < 16; ++t) {
    f16x8 kr[4], vr[4];
    bool pf = (t + 1 < 16);
    if (pf) {  // T14 issue-early: next tile's global loads
      int kv0 = kvbase + (t + 1) * 64;
      const f16* Kt = Kbase + (size_t)kv0 * 128;
#pragma unroll
      for (int r = 0; r < 4; ++r) kr[r] = *(const f16x8*)(Kt + (r * 256 + tid) * 8);
#pragma unroll
      for (int u = 0; u < 4; ++u)
        vr[u] = *(const f16x8*)(Vbase + (size_t)vrow * 4096 + kv0 + h2i * 32 + u * 8);
    }

    // ---- S^T = K . Q^T ----
    f32x16 s2[2];
    __builtin_amdgcn_s_setprio(1);
#pragma unroll
    for (int t2 = 0; t2 < 2; ++t2) {
#pragma unroll
      for (int r = 0; r < 16; ++r) s2[t2][r] = 0.f;
      int row = t2 * 32 + col;
      const char* kb = (const char*)Ks + row * 256;
      int sk = swzr(row);
#pragma unroll
      for (int ks = 0; ks < 8; ++ks) {
        f16x8 ak = *(const f16x8*)(kb + ((ks * 32 + hi * 16) ^ sk));
        s2[t2] = MFMA32(ak, bq[ks], s2[t2]);
      }
    }
    __builtin_amdgcn_s_setprio(0);

    // ---- per-lane online softmax, max3-shaped 32-value tree ----
    float w0 = fmaxf(fmaxf(s2[0][0], s2[0][1]), s2[0][2]);
    float w1 = fmaxf(fmaxf(s2[0][3], s2[0][4]), s2[0][5]);
    float w2 = fmaxf(fmaxf(s2[0][6], s2[0][7]), s2[0][8]);
    float w3 = fmaxf(fmaxf(s2[0][9], s2[0][10]), s2[0][11]);
    float w4 = fmaxf(fmaxf(s2[0][12], s2[0][13]), s2[0][14]);
    float w5 = fmaxf(fmaxf(s2[0][15], s2[1][0]), s2[1][1]);
    float w6 = fmaxf(fmaxf(s2[1][2], s2[1][3]), s2[1][4]);
    float w7 = fmaxf(fmaxf(s2[1][5], s2[1][6]), s2[1][7]);
    float w8 = fmaxf(fmaxf(s2[1][8], s2[1][9]), s2[1][10]);
    float w9 = fmaxf(fmaxf(s2[1][11], s2[1][12]), s2[1][13]);
    float wb = fmaxf(s2[1][14], s2[1][15]);
    float x0 = fmaxf(fmaxf(w0, w1), w2);
    float x1 = fmaxf(fmaxf(w3, w4), w5);
    float x2 = fmaxf(fmaxf(w6, w7), w8);
    float pm = fmaxf(fmaxf(x0, x1), fmaxf(x2, fmaxf(w9, wb)));
    pm = fmaxf(pm, __shfl_xor(pm, 32));
    if (pm > m + 8.f) {  // T13 defer-max
      float sc = __expf(m - pm);
      m = pm;
      nmL = -m * L;
#pragma unroll
      for (int i = 0; i < 4; ++i) lv[i] *= sc;
#pragma unroll
      for (int dt = 0; dt < 4; ++dt)
#pragma unroll
        for (int r = 0; r < 16; ++r) yacc[dt][r] *= sc;
    }
#pragma unroll
    for (int t2i = 0; t2i < 2; ++t2i)
#pragma unroll
      for (int r = 0; r < 16; ++r) s2[t2i][r] = exp2f(fmaf(s2[t2i][r], L, nmL));

    // ---- P -> f16 frags (lane-local; V pre-permuted), l via dot2 ----
    f16x8 pfr[4];
#pragma unroll
    for (int t2i = 0; t2i < 2; ++t2i)
#pragma unroll
      for (int k1 = 0; k1 < 2; ++k1) {
        f16x8 f;
#pragma unroll
        for (int c = 0; c < 8; ++c) f[c] = (f16)s2[t2i][8 * k1 + c];
        pfr[t2i * 2 + k1] = f;
      }
#if defined(HAS_FDOT2)
    {
      h2 one2 = {1.0f, 1.0f};
#pragma unroll
      for (int i = 0; i < 4; ++i) {
        const h2* pp = (const h2*)&pfr[i];
#pragma unroll
        for (int j = 0; j < 4; ++j)
          lv[j] = __builtin_amdgcn_fdot2(pp[j], one2, lv[j], false);
      }
    }
#else
#pragma unroll
    for (int i = 0; i < 4; ++i)
#pragma unroll
      for (int j = 0; j < 4; ++j)
        lv[j] += (float)pfr[i][2 * j] + (float)pfr[i][2 * j + 1];
#endif

    // ---- Y^T += V . P ----
    __builtin_amdgcn_s_setprio(1);
#pragma unroll
    for (int kstep = 0; kstep < 4; ++kstep) {
#pragma unroll
      for (int dt = 0; dt < 4; ++dt) {
        int row = dt * 32 + col;
        f16x8 av = *(const f16x8*)((const char*)Vs + row * 128 +
                                   ((kstep * 32 + hi * 16) ^ swzr(row)));
        yacc[dt] = MFMA32(av, pfr[kstep], yacc[dt]);
      }
    }
    __builtin_amdgcn_s_setprio(0);

    __syncthreads();  // all waves done reading Ks/Vs for tile t
    if (pf) {         // T14 write-late: store tile t+1
#pragma unroll
      for (int r = 0; r < 4; ++r) {
        int row = r * 16 + krow;
        *(f16x8*)((char*)Ks + row * 256 + (kcolb ^ swzr(row))) = kr[r];
      }
      f16x8 c0, c1, c2, c3;
#pragma unroll
      for (int e = 0; e < 4; ++e) {
        c0[e] = vr[0][e];     c0[4 + e] = vr[1][e];
        c1[e] = vr[0][4 + e]; c1[4 + e] = vr[1][4 + e];
        c2[e] = vr[2][e];     c2[4 + e] = vr[3][e];
        c3[e] = vr[2][4 + e]; c3[4 + e] = vr[3][4 + e];
      }
      char* vb = (char*)Vs + vrow * 128;
      *(f16x8*)(vb + ((h2i * 64 + 0) ^ sv)) = c0;
      *(f16x8*)(vb + ((h2i * 64 + 16) ^ sv)) = c1;
      *(f16x8*)(vb + ((h2i * 64 + 32) ^ sv)) = c2;
      *(f16x8*)(vb + ((h2i * 64 + 48) ^ sv)) = c3;
    }
    __syncthreads();  // writes visible for tile t+1
  }

  float l = (lv[0] + lv[1]) + (lv[2] + lv[3]);
  l += __shfl_xor(l, 32);

  int rowG = b * 4096 + qbase + w * 32 + col;
  f16* yo = Yp + ((size_t)s * 32768 + rowG) * 128;
  float inv = 1.0f / l;
#pragma unroll
  for (int dt = 0; dt < 4; ++dt)
#pragma unroll
    for (int a = 0; a < 4; ++a) {
      f16x4 ov = {(f16)(yacc[dt][4 * a] * inv), (f16)(yacc[dt][4 * a + 1] * inv),
                  (f16)(yacc[dt][4 * a + 2] * inv), (f16)(yacc[dt][4 * a + 3] * inv)};
      *(f16x4*)(yo + dt * 32 + a * 8 + hi * 4) = ov;
    }
  if (hi == 0) ml[s * 32768 + rowG] = make_float2(m, l);
}

// ---------------- kernel 3: 4-way combine + epilogue GEMM + bias + residual ----
__global__ __launch_bounds__(256) void epi_k(const f16* __restrict__ Yp,
                                             const float2* __restrict__ ml,
                                             const f16* __restrict__ Wepi,
                                             const float* __restrict__ Wb,
                                             const float* __restrict__ x,
                                             float* __restrict__ out) {
  int b = blockIdx.x >> 6, nt = blockIdx.x & 63;
  int nbase = nt * 64;
  int w = threadIdx.x >> 6, lane = threadIdx.x & 63;
  int lr = lane & 15, lhi = lane >> 4;
  f16x8 by[4][4];
#pragma unroll
  for (int n4 = 0; n4 < 4; ++n4) {
    int row = b * 4096 + nbase + n4 * 16 + lr;
    float2 m0 = ml[row], m1 = ml[32768 + row], m2 = ml[65536 + row], m3 = ml[98304 + row];
    float mm = fmaxf(fmaxf(m0.x, m1.x), fmaxf(m2.x, m3.x));
    float w0 = m0.y * __expf(m0.x - mm), w1 = m1.y * __expf(m1.x - mm);
    float w2 = m2.y * __expf(m2.x - mm), w3 = m3.y * __expf(m3.x - mm);
    float inv = 1.f / (w0 + w1 + w2 + w3);
    w0 *= inv; w1 *= inv; w2 *= inv; w3 *= inv;
    size_t rb = (size_t)row * 128;
#pragma unroll
    for (int ks = 0; ks < 4; ++ks) {
      int eo = ks * 32 + lhi * 8;
      f16x8 a0 = *(const f16x8*)(Yp + rb + eo);
      f16x8 a1 = *(const f16x8*)(Yp + (size_t)32768 * 128 + rb + eo);
      f16x8 a2 = *(const f16x8*)(Yp + (size_t)65536 * 128 + rb + eo);
      f16x8 a3 = *(const f16x8*)(Yp + (size_t)98304 * 128 + rb + eo);
      f16x8 o;
#pragma unroll
      for (int e = 0; e < 8; ++e)
        o[e] = (f16)(w0 * (float)a0[e] + w1 * (float)a1[e] + w2 * (float)a2[e] +
                     w3 * (float)a3[e]);
      by[n4][ks] = o;
    }
  }
#pragma unroll
  for (int ot = 0; ot < 4; ++ot) {
    int o0 = w * 64 + ot * 16;
    const f16x8* wr = (const f16x8*)(Wepi + (size_t)(o0 + lr) * 128);
    f16x8 a[4];
#pragma unroll
    for (int ks = 0; ks < 4; ++ks) a[ks] = wr[ks * 4 + lhi];
#pragma unroll
    for (int n4 = 0; n4 < 4; ++n4) {
      f32x4 acc = {0.f, 0.f, 0.f, 0.f};
#pragma unroll
      for (int ks = 0; ks < 4; ++ks) acc = MFMA16(a[ks], by[n4][ks], acc);
#pragma unroll
      for (int r = 0; r < 4; ++r) {
        int o = o0 + lhi * 4 + r;
        int n = nbase + n4 * 16 + lr;
        size_t idx = ((size_t)b * 256 + o) * 4096 + n;
        out[idx] = x[idx] + Wb[o] + acc[r];
      }
    }
  }
}

extern "C" void kernel_launch(void* const* d_in, const int* in_sizes, int n_in,
                              void* d_out, int out_size, void* d_ws, size_t ws_size,
                              hipStream_t stream) {
  const float* x       = (const float*)d_in[0];
  const float* g_w     = (const float*)d_in[1];
  const float* g_b     = (const float*)d_in[2];
  const float* theta_w = (const float*)d_in[3];
  const float* theta_b = (const float*)d_in[4];
  const float* phi_w   = (const float*)d_in[5];
  const float* phi_b   = (const float*)d_in[6];
  const float* W_w     = (const float*)d_in[7];
  const float* W_b     = (const float*)d_in[8];
  float* out = (float*)d_out;

  f16* Q    = (f16*)d_ws;                       // [8,4096,128] 8MB
  f16* Kk   = Q + (size_t)8 * 4096 * 128;       // 8MB
  f16* Vt   = Kk + (size_t)8 * 4096 * 128;      // 8MB
  f16* Wall = Vt + (size_t)8 * 4096 * 128;      // [384,256]
  f16* Wepi = Wall + 384 * 256;                 // [256,128]
  float2* ml = (float2*)(Wepi + 256 * 128);     // [4][32768] 1MB
  f16* Yp   = (f16*)(ml + 4 * 32768);           // [4][32768][128] 32MB (~57.3MB total)

  wcvt_k<<<512, 256, 0, stream>>>(theta_w, phi_w, g_w, W_w, Wall, Wepi);
  proj_k<<<512, 256, 0, stream>>>(x, Wall, theta_b, phi_b, g_b, Q, Kk, Vt);
  attn_k<<<1024, 256, 0, stream>>>(Q, Kk, Vt, Yp, ml);
  epi_k<<<512, 256, 0, stream>>>(Yp, ml, Wepi, W_b, x, out);
}

// Round 10
// 195.872 us; speedup vs baseline: 1.8148x; 1.8148x over previous
//
#include <hip/hip_runtime.h>

typedef _Float16 f16;
typedef _Float16 f16x4 __attribute__((ext_vector_type(4)));
typedef _Float16 f16x8 __attribute__((ext_vector_type(8)));
typedef __fp16 h2 __attribute__((ext_vector_type(2)));
typedef float f32x4 __attribute__((ext_vector_type(4)));
typedef float f32x16 __attribute__((ext_vector_type(16)));

#define MFMA16(a, b, c) __builtin_amdgcn_mfma_f32_16x16x32_f16(a, b, c, 0, 0, 0)
#define MFMA32(a, b, c) __builtin_amdgcn_mfma_f32_32x32x16_f16(a, b, c, 0, 0, 0)

#if defined(__has_builtin)
#if __has_builtin(__builtin_amdgcn_fdot2)
#define HAS_FDOT2 1
#endif
#endif

__device__ __forceinline__ int swzr(int row) { return ((row & 7) << 4) ^ ((row & 8) << 2); }

// ---------------- kernel 0: convert weights to fp16 ----------------
__global__ __launch_bounds__(256) void wcvt_k(
    const float* __restrict__ tw, const float* __restrict__ pw,
    const float* __restrict__ gw, const float* __restrict__ ww,
    f16* __restrict__ Wall, f16* __restrict__ Wepi) {
  int i = blockIdx.x * 256 + threadIdx.x;
  if (i < 384 * 256) {
    int c = i >> 8, cp = i & 255;
    float v = (c < 128) ? tw[c * 256 + cp]
            : (c < 256) ? pw[(c - 128) * 256 + cp]
                        : gw[(c - 256) * 256 + cp];
    Wall[i] = (f16)v;
  }
  int j = i - 384 * 256;
  if (j >= 0 && j < 256 * 128) Wepi[j] = (f16)ww[j];
}

// ---------------- kernel 1: projection GEMM, reads x natively ----------------
__global__ __launch_bounds__(256) void proj_k(
    const float* __restrict__ x, const f16* __restrict__ Wall,
    const float* __restrict__ tb, const float* __restrict__ pb,
    const float* __restrict__ gb, f16* __restrict__ Q, f16* __restrict__ K,
    f16* __restrict__ Vt) {
  __shared__ f16 xs[64 * 264];
  __shared__ f16 vs[128 * 65];
  int b = blockIdx.x >> 6, nt = blockIdx.x & 63;
  int nbase = nt * 64;
  int tid = threadIdx.x;

  int nq = tid & 15, kq0 = tid >> 4;
#pragma unroll
  for (int p = 0; p < 4; ++p) {
    int kq = kq0 + 16 * p;
    float4 ld[4];
#pragma unroll
    for (int j = 0; j < 4; ++j)
      ld[j] = *(const float4*)(x + ((size_t)b * 256 + 4 * kq + j) * 4096 + nbase + 4 * nq);
#pragma unroll
    for (int e = 0; e < 4; ++e) {
      f16x4 wv = {(f16)((&ld[0].x)[e]), (f16)((&ld[1].x)[e]), (f16)((&ld[2].x)[e]),
                  (f16)((&ld[3].x)[e])};
      *(f16x4*)(&xs[(4 * nq + e) * 264 + 4 * kq]) = wv;
    }
  }
  __syncthreads();

  int w = tid >> 6, lane = tid & 63;
  int lr = lane & 15, lhi = lane >> 4;
  f16x8 a[8];
#pragma unroll
  for (int ks = 0; ks < 8; ++ks)
    a[ks] = *(const f16x8*)(&xs[(w * 16 + lr) * 264 + ks * 32 + lhi * 8]);
  f32x4 acc[24];
#pragma unroll
  for (int ct = 0; ct < 24; ++ct) {
    acc[ct] = {0.f, 0.f, 0.f, 0.f};
    const f16x8* wr = (const f16x8*)(Wall + (size_t)(ct * 16 + lr) * 256);
#pragma unroll
    for (int ks = 0; ks < 8; ++ks) acc[ct] = MFMA16(a[ks], wr[ks * 4 + lhi], acc[ct]);
  }
  int nloc = w * 16 + lhi * 4;
#pragma unroll
  for (int ct = 0; ct < 24; ++ct) {
    int c = ct * 16 + lr;
    float bias = (c < 128) ? tb[c] : (c < 256) ? pb[c - 128] : gb[c - 256];
#pragma unroll
    for (int r = 0; r < 4; ++r) {
      float v = acc[ct][r] + bias;
      int n = nbase + nloc + r;
      if (c < 128)
        Q[((size_t)b * 4096 + n) * 128 + c] = (f16)v;
      else if (c < 256)
        K[((size_t)b * 4096 + n) * 128 + (c - 128)] = (f16)v;
      else
        vs[(c - 256) * 65 + nloc + r] = (f16)v;
    }
  }
  __syncthreads();
  f16* vo = Vt + (size_t)b * 128 * 4096 + nbase;
  for (int rep = 0; rep < 32; ++rep) {
    int idx = rep * 256 + threadIdx.x;
    int c = idx >> 6, j = idx & 63;
    vo[(size_t)c * 4096 + j] = vs[c * 65 + j];
  }
}

// ---------------- kernel 2: flash attention, KV-split-2, dbuf, T15 QKT-ahead ----
// Two S-states (sA/sB, static names): QK^T(t+1) issued at END of iter t, so
// softmax(t+1) consumes drained MFMA results and MFMA/VALU overlap per-wave.
// Registers ~225 < 256 cap (2 waves/SIMD). R5/R9 lesson: never cap below need.
__global__ __launch_bounds__(256, 2) void attn_k(const f16* __restrict__ Q,
                                                 const f16* __restrict__ K,
                                                 const f16* __restrict__ Vt,
                                                 f16* __restrict__ Yp,
                                                 float2* __restrict__ ml) {
  __shared__ f16 Ks[2][64 * 128];
  __shared__ f16 Vs[2][128 * 64];
  const float L = 1.44269504f;
  int swzid = ((blockIdx.x & 7) << 6) | ((int)blockIdx.x >> 3);
  int b = swzid >> 6, rem = swzid & 63;
  int qt = rem >> 1, half = rem & 1;
  int qbase = qt * 128;
  int kvbase = half << 11;
  int tid = threadIdx.x;
  int w = tid >> 6, lane = tid & 63;
  int col = lane & 31, hi = lane >> 5;

  const f16* Qr = Q + ((size_t)b * 4096 + qbase + w * 32 + col) * 128;
  f16x8 bq[8];
#pragma unroll
  for (int ks = 0; ks < 8; ++ks) bq[ks] = *(const f16x8*)(Qr + ks * 16 + hi * 8);

  f32x16 yacc[4];
#pragma unroll
  for (int dt = 0; dt < 4; ++dt)
#pragma unroll
    for (int r = 0; r < 16; ++r) yacc[dt][r] = 0.f;
  float lv[4] = {0.f, 0.f, 0.f, 0.f};
  float m = -1e30f, nmL = 1e30f;

  const f16* Kbase = K + (size_t)b * 4096 * 128;
  const f16* Vbase = Vt + (size_t)b * 128 * 4096;

  int krow = tid >> 4, kcolb = (tid & 15) * 16;
  int vrow = tid >> 1, h2i = tid & 1;
  int sv = swzr(vrow);

  f16x8 kr[4], vr[4];

  auto issue_loads = [&](int t) {  // T14 issue-early into kr/vr
    int kv0 = kvbase + t * 64;
    const f16* Kt = Kbase + (size_t)kv0 * 128;
#pragma unroll
    for (int r = 0; r < 4; ++r) kr[r] = *(const f16x8*)(Kt + (r * 256 + tid) * 8);
#pragma unroll
    for (int u = 0; u < 4; ++u)
      vr[u] = *(const f16x8*)(Vbase + (size_t)vrow * 4096 + kv0 + h2i * 32 + u * 8);
  };
  auto stage_write = [&](int buf) {  // write kr/vr into LDS buf (V kv-permuted)
#pragma unroll
    for (int r = 0; r < 4; ++r) {
      int row = r * 16 + krow;
      *(f16x8*)((char*)Ks[buf] + row * 256 + (kcolb ^ swzr(row))) = kr[r];
    }
    f16x8 c0, c1, c2, c3;
#pragma unroll
    for (int e = 0; e < 4; ++e) {
      c0[e] = vr[0][e];     c0[4 + e] = vr[1][e];
      c1[e] = vr[0][4 + e]; c1[4 + e] = vr[1][4 + e];
      c2[e] = vr[2][e];     c2[4 + e] = vr[3][e];
      c3[e] = vr[2][4 + e]; c3[4 + e] = vr[3][4 + e];
    }
    char* vb = (char*)Vs[buf] + vrow * 128;
    *(f16x8*)(vb + ((h2i * 64 + 0) ^ sv)) = c0;
    *(f16x8*)(vb + ((h2i * 64 + 16) ^ sv)) = c1;
    *(f16x8*)(vb + ((h2i * 64 + 32) ^ sv)) = c2;
    *(f16x8*)(vb + ((h2i * 64 + 48) ^ sv)) = c3;
  };
  auto do_qkt = [&](int buf, f32x16* s2) {
    __builtin_amdgcn_s_setprio(1);
#pragma unroll
    for (int t2 = 0; t2 < 2; ++t2) {
#pragma unroll
      for (int r = 0; r < 16; ++r) s2[t2][r] = 0.f;
      int row = t2 * 32 + col;
      const char* kb = (const char*)Ks[buf] + row * 256;
      int sk = swzr(row);
#pragma unroll
      for (int ks = 0; ks < 8; ++ks) {
        f16x8 ak = *(const f16x8*)(kb + ((ks * 32 + hi * 16) ^ sk));
        s2[t2] = MFMA32(ak, bq[ks], s2[t2]);
      }
    }
    __builtin_amdgcn_s_setprio(0);
  };
  auto do_sm_pv = [&](f32x16* s2, int buf, int t) {
    // max3-shaped 32-value tree
    float w0 = fmaxf(fmaxf(s2[0][0], s2[0][1]), s2[0][2]);
    float w1 = fmaxf(fmaxf(s2[0][3], s2[0][4]), s2[0][5]);
    float w2 = fmaxf(fmaxf(s2[0][6], s2[0][7]), s2[0][8]);
    float w3 = fmaxf(fmaxf(s2[0][9], s2[0][10]), s2[0][11]);
    float w4 = fmaxf(fmaxf(s2[0][12], s2[0][13]), s2[0][14]);
    float w5 = fmaxf(fmaxf(s2[0][15], s2[1][0]), s2[1][1]);
    float w6 = fmaxf(fmaxf(s2[1][2], s2[1][3]), s2[1][4]);
    float w7 = fmaxf(fmaxf(s2[1][5], s2[1][6]), s2[1][7]);
    float w8 = fmaxf(fmaxf(s2[1][8], s2[1][9]), s2[1][10]);
    float w9 = fmaxf(fmaxf(s2[1][11], s2[1][12]), s2[1][13]);
    float wb = fmaxf(s2[1][14], s2[1][15]);
    float x0 = fmaxf(fmaxf(w0, w1), w2);
    float x1 = fmaxf(fmaxf(w3, w4), w5);
    float x2 = fmaxf(fmaxf(w6, w7), w8);
    float pm = fmaxf(fmaxf(x0, x1), fmaxf(x2, fmaxf(w9, wb)));
    pm = fmaxf(pm, __shfl_xor(pm, 32));
    if (pm > m + 8.f) {  // T13 defer-max
      float sc = __expf(m - pm);
      m = pm;
      nmL = -m * L;
#pragma unroll
      for (int i = 0; i < 4; ++i) lv[i] *= sc;
#pragma unroll
      for (int dt = 0; dt < 4; ++dt)
#pragma unroll
        for (int r = 0; r < 16; ++r) yacc[dt][r] *= sc;
    }
#pragma unroll
    for (int t2i = 0; t2i < 2; ++t2i)
#pragma unroll
      for (int r = 0; r < 16; ++r) s2[t2i][r] = exp2f(fmaf(s2[t2i][r], L, nmL));

    f16x8 pfr[4];
#pragma unroll
    for (int t2i = 0; t2i < 2; ++t2i)
#pragma unroll
      for (int k1 = 0; k1 < 2; ++k1) {
        f16x8 f;
#pragma unroll
        for (int c = 0; c < 8; ++c) f[c] = (f16)s2[t2i][8 * k1 + c];
        pfr[t2i * 2 + k1] = f;
      }
#if defined(HAS_FDOT2)
    {
      h2 one2 = {1.0f, 1.0f};
#pragma unroll
      for (int i = 0; i < 4; ++i) {
        const h2* pp = (const h2*)&pfr[i];
#pragma unroll
        for (int j = 0; j < 4; ++j)
          lv[j] = __builtin_amdgcn_fdot2(pp[j], one2, lv[j], false);
      }
    }
#else
#pragma unroll
    for (int i = 0; i < 4; ++i)
#pragma unroll
      for (int j = 0; j < 4; ++j)
        lv[j] += (float)pfr[i][2 * j] + (float)pfr[i][2 * j + 1];
#endif
    // issue next-next tile loads (T14) before PV for latency cover
    if (t + 2 < 32) issue_loads(t + 2);
    __builtin_amdgcn_s_setprio(1);
#pragma unroll
    for (int kstep = 0; kstep < 4; ++kstep) {
#pragma unroll
      for (int dt = 0; dt < 4; ++dt) {
        int row = dt * 32 + col;
        f16x8 av = *(const f16x8*)((const char*)Vs[buf] + row * 128 +
                                   ((kstep * 32 + hi * 16) ^ swzr(row)));
        yacc[dt] = MFMA32(av, pfr[kstep], yacc[dt]);
      }
    }
    __builtin_amdgcn_s_setprio(0);
  };

  // prologue: stage tile0 -> buf0; issue tile1 loads; QKT(0) -> sA
  f32x16 sA[2], sB[2];
  issue_loads(0);
  stage_write(0);
  issue_loads(1);
  __syncthreads();
  do_qkt(0, sA);

  for (int t = 0; t < 32; t += 2) {
    // ---- iter t (state sA, cur buf0, next buf1) ----
    stage_write(1);        // tile t+1 (kr/vr)
    do_sm_pv(sA, 0, t);    // softmax+PV tile t; issues loads t+2
    __syncthreads();
    do_qkt(1, sB);         // QKT tile t+1
    // ---- iter t+1 (state sB, cur buf1, next buf0) ----
    if (t + 2 < 32) stage_write(0);  // tile t+2
    do_sm_pv(sB, 1, t + 1);          // softmax+PV tile t+1; issues loads t+3
    __syncthreads();
    if (t + 2 < 32) do_qkt(0, sA);   // QKT tile t+2
  }

  float l = (lv[0] + lv[1]) + (lv[2] + lv[3]);
  l += __shfl_xor(l, 32);

  int rowG = b * 4096 + qbase + w * 32 + col;
  f16* yo = Yp + ((size_t)half * 32768 + rowG) * 128;
  float inv = 1.0f / l;
#pragma unroll
  for (int dt = 0; dt < 4; ++dt)
#pragma unroll
    for (int a = 0; a < 4; ++a) {
      f16x4 ov = {(f16)(yacc[dt][4 * a] * inv), (f16)(yacc[dt][4 * a + 1] * inv),
                  (f16)(yacc[dt][4 * a + 2] * inv), (f16)(yacc[dt][4 * a + 3] * inv)};
      *(f16x4*)(yo + dt * 32 + a * 8 + hi * 4) = ov;
    }
  if (hi == 0) ml[half * 32768 + rowG] = make_float2(m, l);
}

// ---------------- kernel 3: 2-way combine + epilogue GEMM + bias + residual ----
__global__ __launch_bounds__(256) void epi_k(const f16* __restrict__ Yp,
                                             const float2* __restrict__ ml,
                                             const f16* __restrict__ Wepi,
                                             const float* __restrict__ Wb,
                                             const float* __restrict__ x,
                                             float* __restrict__ out) {
  int b = blockIdx.x >> 6, nt = blockIdx.x & 63;
  int nbase = nt * 64;
  int w = threadIdx.x >> 6, lane = threadIdx.x & 63;
  int lr = lane & 15, lhi = lane >> 4;
  const f16* yb1 = Yp + (size_t)32768 * 128;
  f16x8 by[4][4];
#pragma unroll
  for (int n4 = 0; n4 < 4; ++n4) {
    int row = b * 4096 + nbase + n4 * 16 + lr;
    float2 m0 = ml[row], m1 = ml[32768 + row];
    float mm = fmaxf(m0.x, m1.x);
    float w0 = m0.y * __expf(m0.x - mm), w1 = m1.y * __expf(m1.x - mm);
    float inv = 1.f / (w0 + w1);
    w0 *= inv;
    w1 *= inv;
    size_t rb = (size_t)row * 128;
#pragma unroll
    for (int ks = 0; ks < 4; ++ks) {
      int eo = ks * 32 + lhi * 8;
      f16x8 a0 = *(const f16x8*)(Yp + rb + eo);
      f16x8 a1 = *(const f16x8*)(yb1 + rb + eo);
      f16x8 o;
#pragma unroll
      for (int e = 0; e < 8; ++e) o[e] = (f16)(w0 * (float)a0[e] + w1 * (float)a1[e]);
      by[n4][ks] = o;
    }
  }
#pragma unroll
  for (int ot = 0; ot < 4; ++ot) {
    int o0 = w * 64 + ot * 16;
    const f16x8* wr = (const f16x8*)(Wepi + (size_t)(o0 + lr) * 128);
    f16x8 a[4];
#pragma unroll
    for (int ks = 0; ks < 4; ++ks) a[ks] = wr[ks * 4 + lhi];
#pragma unroll
    for (int n4 = 0; n4 < 4; ++n4) {
      f32x4 acc = {0.f, 0.f, 0.f, 0.f};
#pragma unroll
      for (int ks = 0; ks < 4; ++ks) acc = MFMA16(a[ks], by[n4][ks], acc);
#pragma unroll
      for (int r = 0; r < 4; ++r) {
        int o = o0 + lhi * 4 + r;
        int n = nbase + n4 * 16 + lr;
        size_t idx = ((size_t)b * 256 + o) * 4096 + n;
        out[idx] = x[idx] + Wb[o] + acc[r];
      }
    }
  }
}

extern "C" void kernel_launch(void* const* d_in, const int* in_sizes, int n_in,
                              void* d_out, int out_size, void* d_ws, size_t ws_size,
                              hipStream_t stream) {
  const float* x       = (const float*)d_in[0];
  const float* g_w     = (const float*)d_in[1];
  const float* g_b     = (const float*)d_in[2];
  const float* theta_w = (const float*)d_in[3];
  const float* theta_b = (const float*)d_in[4];
  const float* phi_w   = (const float*)d_in[5];
  const float* phi_b   = (const float*)d_in[6];
  const float* W_w     = (const float*)d_in[7];
  const float* W_b     = (const float*)d_in[8];
  float* out = (float*)d_out;

  f16* Q    = (f16*)d_ws;                       // [8,4096,128] 8MB
  f16* Kk   = Q + (size_t)8 * 4096 * 128;       // 8MB
  f16* Vt   = Kk + (size_t)8 * 4096 * 128;      // 8MB
  f16* Wall = Vt + (size_t)8 * 4096 * 128;      // [384,256]
  f16* Wepi = Wall + 384 * 256;                 // [256,128]
  float2* ml = (float2*)(Wepi + 256 * 128);     // [2][32768] 0.5MB
  f16* Yp   = (f16*)(ml + 2 * 32768);           // [2][32768][128] 16MB (~41MB total)

  wcvt_k<<<512, 256, 0, stream>>>(theta_w, phi_w, g_w, W_w, Wall, Wepi);
  proj_k<<<512, 256, 0, stream>>>(x, Wall, theta_b, phi_b, g_b, Q, Kk, Vt);
  attn_k<<<512, 256, 0, stream>>>(Q, Kk, Vt, Yp, ml);
  epi_k<<<512, 256, 0, stream>>>(Yp, ml, Wepi, W_b, x, out);
}

// Round 11
// 194.235 us; speedup vs baseline: 1.8301x; 1.0084x over previous
//
#include <hip/hip_runtime.h>

typedef _Float16 f16;
typedef _Float16 f16x4 __attribute__((ext_vector_type(4)));
typedef _Float16 f16x8 __attribute__((ext_vector_type(8)));
typedef __fp16 h2 __attribute__((ext_vector_type(2)));
typedef float f32x4 __attribute__((ext_vector_type(4)));
typedef float f32x16 __attribute__((ext_vector_type(16)));

#define MFMA16(a, b, c) __builtin_amdgcn_mfma_f32_16x16x32_f16(a, b, c, 0, 0, 0)
#define MFMA32(a, b, c) __builtin_amdgcn_mfma_f32_32x32x16_f16(a, b, c, 0, 0, 0)

#if defined(__has_builtin)
#if __has_builtin(__builtin_amdgcn_fdot2)
#define HAS_FDOT2 1
#endif
#endif

typedef const __attribute__((address_space(1))) void gvoid;
typedef __attribute__((address_space(3))) void lvoid;
#define GLDS16(g, l) __builtin_amdgcn_global_load_lds((gvoid*)(g), (lvoid*)(l), 16, 0, 0)

__device__ __forceinline__ int swzr(int row) { return ((row & 7) << 4) ^ ((row & 8) << 2); }

// ---------------- kernel 0: convert weights to fp16 ----------------
__global__ __launch_bounds__(256) void wcvt_k(
    const float* __restrict__ tw, const float* __restrict__ pw,
    const float* __restrict__ gw, const float* __restrict__ ww,
    f16* __restrict__ Wall, f16* __restrict__ Wepi) {
  int i = blockIdx.x * 256 + threadIdx.x;
  if (i < 384 * 256) {
    int c = i >> 8, cp = i & 255;
    float v = (c < 128) ? tw[c * 256 + cp]
            : (c < 256) ? pw[(c - 128) * 256 + cp]
                        : gw[(c - 256) * 256 + cp];
    Wall[i] = (f16)v;
  }
  int j = i - 384 * 256;
  if (j >= 0 && j < 256 * 128) Wepi[j] = (f16)ww[j];
}

// ---------------- kernel 1: projection GEMM, reads x natively ----------------
// V is written KV-PERMUTED (bits 2<->3 of kv-local index) so attention's PV
// B-fragment is the lane's own P registers (no cross-lane, no LDS P buffer).
__global__ __launch_bounds__(256) void proj_k(
    const float* __restrict__ x, const f16* __restrict__ Wall,
    const float* __restrict__ tb, const float* __restrict__ pb,
    const float* __restrict__ gb, f16* __restrict__ Q, f16* __restrict__ K,
    f16* __restrict__ Vt) {
  __shared__ f16 xs[64 * 264];
  __shared__ f16 vs[128 * 65];
  int b = blockIdx.x >> 6, nt = blockIdx.x & 63;
  int nbase = nt * 64;
  int tid = threadIdx.x;

  int nq = tid & 15, kq0 = tid >> 4;
#pragma unroll
  for (int p = 0; p < 4; ++p) {
    int kq = kq0 + 16 * p;
    float4 ld[4];
#pragma unroll
    for (int j = 0; j < 4; ++j)
      ld[j] = *(const float4*)(x + ((size_t)b * 256 + 4 * kq + j) * 4096 + nbase + 4 * nq);
#pragma unroll
    for (int e = 0; e < 4; ++e) {
      f16x4 wv = {(f16)((&ld[0].x)[e]), (f16)((&ld[1].x)[e]), (f16)((&ld[2].x)[e]),
                  (f16)((&ld[3].x)[e])};
      *(f16x4*)(&xs[(4 * nq + e) * 264 + 4 * kq]) = wv;
    }
  }
  __syncthreads();

  int w = tid >> 6, lane = tid & 63;
  int lr = lane & 15, lhi = lane >> 4;
  f16x8 a[8];
#pragma unroll
  for (int ks = 0; ks < 8; ++ks)
    a[ks] = *(const f16x8*)(&xs[(w * 16 + lr) * 264 + ks * 32 + lhi * 8]);
  f32x4 acc[24];
#pragma unroll
  for (int ct = 0; ct < 24; ++ct) {
    acc[ct] = {0.f, 0.f, 0.f, 0.f};
    const f16x8* wr = (const f16x8*)(Wall + (size_t)(ct * 16 + lr) * 256);
#pragma unroll
    for (int ks = 0; ks < 8; ++ks) acc[ct] = MFMA16(a[ks], wr[ks * 4 + lhi], acc[ct]);
  }
  int nloc = w * 16 + lhi * 4;
#pragma unroll
  for (int ct = 0; ct < 24; ++ct) {
    int c = ct * 16 + lr;
    float bias = (c < 128) ? tb[c] : (c < 256) ? pb[c - 128] : gb[c - 256];
#pragma unroll
    for (int r = 0; r < 4; ++r) {
      float v = acc[ct][r] + bias;
      int n = nbase + nloc + r;
      if (c < 128)
        Q[((size_t)b * 4096 + n) * 128 + c] = (f16)v;
      else if (c < 256)
        K[((size_t)b * 4096 + n) * 128 + (c - 128)] = (f16)v;
      else
        vs[(c - 256) * 65 + nloc + r] = (f16)v;
    }
  }
  __syncthreads();
  f16* vo = Vt + (size_t)b * 128 * 4096 + nbase;
  for (int rep = 0; rep < 32; ++rep) {
    int idx = rep * 256 + threadIdx.x;
    int c = idx >> 6, j = idx & 63;
    int jp = (j & ~12) | ((j & 4) << 1) | ((j & 8) >> 1);  // kv bits 2<->3
    vo[(size_t)c * 4096 + jp] = vs[c * 65 + j];
  }
}

// ---------------- kernel 2: flash attention, KVBLK=32, DMA staging, split-4 ----
// global_load_lds staging (no staging VGPRs/VALU): LDS dest linear, swizzle via
// per-lane GLOBAL source address (m173 pattern). KVBLK=32 halves s2/pfr regs ->
// ~155 unified regs -> __launch_bounds__(256,3) = 3 waves/SIMD, no spill.
// Loop = m97 2-phase: 1 barrier/iter; DMA(t+1) issued right after barrier.
__global__ __launch_bounds__(256, 3) void attn_k(const f16* __restrict__ Q,
                                                 const f16* __restrict__ K,
                                                 const f16* __restrict__ Vt,
                                                 f16* __restrict__ Yp,
                                                 float2* __restrict__ ml) {
  __shared__ f16 Ks[2][32 * 128];  // 8KB per buf, rows=kv (256B), chunk-XOR swzr(row)
  __shared__ f16 Vs[2][128 * 32];  // 8KB per buf, rows=d (64B), chunk-XOR (row&3)<<4
  const float L = 1.44269504f;
  int swzid = ((blockIdx.x & 7) << 7) | ((int)blockIdx.x >> 3);
  int b = swzid >> 7, rem = swzid & 127;
  int qt = rem >> 2, s = rem & 3;
  int qbase = qt * 128;
  int kv0base = s << 10;
  int tid = threadIdx.x;
  int w = tid >> 6, lane = tid & 63;
  int col = lane & 31, hi = lane >> 5;

  const f16* Qr = Q + ((size_t)b * 4096 + qbase + w * 32 + col) * 128;
  f16x8 bq[8];
#pragma unroll
  for (int ks = 0; ks < 8; ++ks) bq[ks] = *(const f16x8*)(Qr + ks * 16 + hi * 8);

  f32x16 yacc[4];
#pragma unroll
  for (int dt = 0; dt < 4; ++dt)
#pragma unroll
    for (int r = 0; r < 16; ++r) yacc[dt][r] = 0.f;
  float lv[4] = {0.f, 0.f, 0.f, 0.f};
  float m = -1e30f, nmL = 1e30f;

  // per-lane DMA source offsets: LDS byte p = w*2048 + call*1024 + lane*16
  unsigned koff[2], voff[2];
#pragma unroll
  for (int c = 0; c < 2; ++c) {
    int p = w * 2048 + c * 1024 + lane * 16;
    int krw = p >> 8, kcb = p & 255;
    koff[c] = (unsigned)(krw * 256 + (kcb ^ swzr(krw)));
    int vrw = p >> 6, vcb = p & 63;
    voff[c] = (unsigned)(vrw * 8192 + (vcb ^ ((vrw & 3) << 4)));
  }
  const char* KbB = (const char*)(K + (size_t)b * 4096 * 128);
  const char* VbB = (const char*)(Vt + (size_t)b * 128 * 4096);
  char* KsB = (char*)&Ks[0][0];
  char* VsB = (char*)&Vs[0][0];

  auto stage = [&](int t, int buf) {
    int kv0 = kv0base + t * 32;
    const char* kb = KbB + (size_t)kv0 * 256;
    const char* vb = VbB + (size_t)kv0 * 2;
    char* kl = KsB + buf * 8192 + w * 2048;
    char* vl = VsB + buf * 8192 + w * 2048;
#pragma unroll
    for (int c = 0; c < 2; ++c) {
      GLDS16(kb + koff[c], kl + c * 1024);
      GLDS16(vb + voff[c], vl + c * 1024);
    }
  };

  stage(0, 0);

  for (int t = 0; t < 32; ++t) {
    int cur = t & 1;
    __syncthreads();  // vmcnt(0) drain by compiler: tile t resident; all synced
    if (t + 1 < 32) stage(t + 1, cur ^ 1);

    // ---- S^T = K . Q^T  (32 kv x 32 q per wave) ----
    f32x16 s2;
#pragma unroll
    for (int r = 0; r < 16; ++r) s2[r] = 0.f;
    __builtin_amdgcn_s_setprio(1);
    {
      const char* kbrow = KsB + cur * 8192 + col * 256;
      int sk = swzr(col);
#pragma unroll
      for (int ks = 0; ks < 8; ++ks) {
        f16x8 ak = *(const f16x8*)(kbrow + ((ks * 32 + hi * 16) ^ sk));
        s2 = MFMA32(ak, bq[ks], s2);
      }
    }
    __builtin_amdgcn_s_setprio(0);

    // ---- per-lane online softmax (16 values) ----
    float a0 = fmaxf(fmaxf(s2[0], s2[1]), s2[2]);
    float a1 = fmaxf(fmaxf(s2[3], s2[4]), s2[5]);
    float a2 = fmaxf(fmaxf(s2[6], s2[7]), s2[8]);
    float a3 = fmaxf(fmaxf(s2[9], s2[10]), s2[11]);
    float a4 = fmaxf(fmaxf(s2[12], s2[13]), s2[14]);
    float pm = fmaxf(fmaxf(fmaxf(a0, a1), fmaxf(a2, a3)), fmaxf(a4, s2[15]));
    pm = fmaxf(pm, __shfl_xor(pm, 32));
    if (pm > m + 8.f) {  // T13 defer-max
      float sc = __expf(m - pm);
      m = pm;
      nmL = -m * L;
#pragma unroll
      for (int i = 0; i < 4; ++i) lv[i] *= sc;
#pragma unroll
      for (int dt = 0; dt < 4; ++dt)
#pragma unroll
        for (int r = 0; r < 16; ++r) yacc[dt][r] *= sc;
    }
#pragma unroll
    for (int r = 0; r < 16; ++r) s2[r] = exp2f(fmaf(s2[r], L, nmL));

    f16x8 pfrA, pfrB;
#pragma unroll
    for (int c = 0; c < 8; ++c) {
      pfrA[c] = (f16)s2[c];
      pfrB[c] = (f16)s2[8 + c];
    }
#if defined(HAS_FDOT2)
    {
      h2 one2 = {1.0f, 1.0f};
      const h2* pa = (const h2*)&pfrA;
      const h2* pb2 = (const h2*)&pfrB;
#pragma unroll
      for (int j = 0; j < 4; ++j) {
        lv[j] = __builtin_amdgcn_fdot2(pa[j], one2, lv[j], false);
        lv[j] = __builtin_amdgcn_fdot2(pb2[j], one2, lv[j], false);
      }
    }
#else
#pragma unroll
    for (int j = 0; j < 4; ++j)
      lv[j] += (float)pfrA[2 * j] + (float)pfrA[2 * j + 1] + (float)pfrB[2 * j] +
               (float)pfrB[2 * j + 1];
#endif

    // ---- Y^T += V . P  (V image pre-permuted; pfr = own regs) ----
    __builtin_amdgcn_s_setprio(1);
    {
      const char* vcur = VsB + cur * 8192;
#pragma unroll
      for (int dt = 0; dt < 4; ++dt) {
        int row = dt * 32 + col;
        const char* vrow_ = vcur + row * 64;
        int sx = (row & 3) << 4;
        f16x8 av0 = *(const f16x8*)(vrow_ + ((hi * 16) ^ sx));
        yacc[dt] = MFMA32(av0, pfrA, yacc[dt]);
        f16x8 av1 = *(const f16x8*)(vrow_ + ((32 + hi * 16) ^ sx));
        yacc[dt] = MFMA32(av1, pfrB, yacc[dt]);
      }
    }
    __builtin_amdgcn_s_setprio(0);
  }

  float l = (lv[0] + lv[1]) + (lv[2] + lv[3]);
  l += __shfl_xor(l, 32);

  int rowG = b * 4096 + qbase + w * 32 + col;
  f16* yo = Yp + ((size_t)s * 32768 + rowG) * 128;
  float inv = 1.0f / l;
#pragma unroll
  for (int dt = 0; dt < 4; ++dt)
#pragma unroll
    for (int a = 0; a < 4; ++a) {
      f16x4 ov = {(f16)(yacc[dt][4 * a] * inv), (f16)(yacc[dt][4 * a + 1] * inv),
                  (f16)(yacc[dt][4 * a + 2] * inv), (f16)(yacc[dt][4 * a + 3] * inv)};
      *(f16x4*)(yo + dt * 32 + a * 8 + hi * 4) = ov;
    }
  if (hi == 0) ml[s * 32768 + rowG] = make_float2(m, l);
}

// ---------------- kernel 3: 4-way combine + epilogue GEMM + bias + residual ----
__global__ __launch_bounds__(256) void epi_k(const f16* __restrict__ Yp,
                                             const float2* __restrict__ ml,
                                             const f16* __restrict__ Wepi,
                                             const float* __restrict__ Wb,
                                             const float* __restrict__ x,
                                             float* __restrict__ out) {
  int b = blockIdx.x >> 6, nt = blockIdx.x & 63;
  int nbase = nt * 64;
  int w = threadIdx.x >> 6, lane = threadIdx.x & 63;
  int lr = lane & 15, lhi = lane >> 4;
  f16x8 by[4][4];
#pragma unroll
  for (int n4 = 0; n4 < 4; ++n4) {
    int row = b * 4096 + nbase + n4 * 16 + lr;
    float2 m0 = ml[row], m1 = ml[32768 + row], m2 = ml[65536 + row], m3 = ml[98304 + row];
    float mm = fmaxf(fmaxf(m0.x, m1.x), fmaxf(m2.x, m3.x));
    float w0 = m0.y * __expf(m0.x - mm), w1 = m1.y * __expf(m1.x - mm);
    float w2 = m2.y * __expf(m2.x - mm), w3 = m3.y * __expf(m3.x - mm);
    float inv = 1.f / (w0 + w1 + w2 + w3);
    w0 *= inv; w1 *= inv; w2 *= inv; w3 *= inv;
    size_t rb = (size_t)row * 128;
#pragma unroll
    for (int ks = 0; ks < 4; ++ks) {
      int eo = ks * 32 + lhi * 8;
      f16x8 a0 = *(const f16x8*)(Yp + rb + eo);
      f16x8 a1 = *(const f16x8*)(Yp + (size_t)32768 * 128 + rb + eo);
      f16x8 a2 = *(const f16x8*)(Yp + (size_t)65536 * 128 + rb + eo);
      f16x8 a3 = *(const f16x8*)(Yp + (size_t)98304 * 128 + rb + eo);
      f16x8 o;
#pragma unroll
      for (int e = 0; e < 8; ++e)
        o[e] = (f16)(w0 * (float)a0[e] + w1 * (float)a1[e] + w2 * (float)a2[e] +
                     w3 * (float)a3[e]);
      by[n4][ks] = o;
    }
  }
#pragma unroll
  for (int ot = 0; ot < 4; ++ot) {
    int o0 = w * 64 + ot * 16;
    const f16x8* wr = (const f16x8*)(Wepi + (size_t)(o0 + lr) * 128);
    f16x8 a[4];
#pragma unroll
    for (int ks = 0; ks < 4; ++ks) a[ks] = wr[ks * 4 + lhi];
#pragma unroll
    for (int n4 = 0; n4 < 4; ++n4) {
      f32x4 acc = {0.f, 0.f, 0.f, 0.f};
#pragma unroll
      for (int ks = 0; ks < 4; ++ks) acc = MFMA16(a[ks], by[n4][ks], acc);
#pragma unroll
      for (int r = 0; r < 4; ++r) {
        int o = o0 + lhi * 4 + r;
        int n = nbase + n4 * 16 + lr;
        size_t idx = ((size_t)b * 256 + o) * 4096 + n;
        out[idx] = x[idx] + Wb[o] + acc[r];
      }
    }
  }
}

extern "C" void kernel_launch(void* const* d_in, const int* in_sizes, int n_in,
                              void* d_out, int out_size, void* d_ws, size_t ws_size,
                              hipStream_t stream) {
  const float* x       = (const float*)d_in[0];
  const float* g_w     = (const float*)d_in[1];
  const float* g_b     = (const float*)d_in[2];
  const float* theta_w = (const float*)d_in[3];
  const float* theta_b = (const float*)d_in[4];
  const float* phi_w   = (const float*)d_in[5];
  const float* phi_b   = (const float*)d_in[6];
  const float* W_w     = (const float*)d_in[7];
  const float* W_b     = (const float*)d_in[8];
  float* out = (float*)d_out;

  f16* Q    = (f16*)d_ws;                       // [8,4096,128] 8MB
  f16* Kk   = Q + (size_t)8 * 4096 * 128;       // 8MB
  f16* Vt   = Kk + (size_t)8 * 4096 * 128;      // 8MB (kv-permuted layout)
  f16* Wall = Vt + (size_t)8 * 4096 * 128;      // [384,256]
  f16* Wepi = Wall + 384 * 256;                 // [256,128]
  float2* ml = (float2*)(Wepi + 256 * 128);     // [4][32768] 1MB
  f16* Yp   = (f16*)(ml + 4 * 32768);           // [4][32768][128] 32MB (~57.3MB total)

  wcvt_k<<<512, 256, 0, stream>>>(theta_w, phi_w, g_w, W_w, Wall, Wepi);
  proj_k<<<512, 256, 0, stream>>>(x, Wall, theta_b, phi_b, g_b, Q, Kk, Vt);
  attn_k<<<1024, 256, 0, stream>>>(Q, Kk, Vt, Yp, ml);
  epi_k<<<512, 256, 0, stream>>>(Yp, ml, Wepi, W_b, x, out);
}